// Round 14
// baseline (207.017 us; speedup 1.0000x reference)
//
#include <hip/hip_runtime.h>
#include <hip/hip_bf16.h>
#include <math.h>

// MHA B=8,S=2048,D=512,H=8,LAT=64,OUT=64. fp32 in/out.
// R27 = R26 (best, 201.6; flash FETCH 139->24.6MB via XCD swizzle) + ONE
// change: the same XCD-bijective remap on qkv's grid, tuned so the co-resident
// set L2-fits: id -> c=id&7, j=id>>3; bh=8c+(j&7), s0=(j>>3)*64. Each XCD's
// ~128 resident blocks span 16 s-tiles x 8 heads: x set 2MB + WT 1.5MB < 4MB
// L2, and consecutive blocks reuse each x-panel across heads -> the
// latency-exposed sync staging loads become L2 hits. Bijective (2048%8==0).
// Everything else byte-identical to R26.
static constexpr int Bn = 8, Sn = 2048, Dn = 512, Hn = 8, LATn = 64, OUTn = 64;

typedef short  bf16x8 __attribute__((ext_vector_type(8)));
typedef float  f32x4  __attribute__((ext_vector_type(4)));

__device__ __forceinline__ unsigned short f2bf(float f) {   // RNE (prep kernels)
    union { float f; unsigned int i; } v; v.f = f;
    unsigned int x = v.i;
    return (unsigned short)((x + 0x7FFFu + ((x >> 16) & 1u)) >> 16);
}
// pack two floats -> two bf16 (round-half-up: bias 2^-17 rel, ~RNE quality)
__device__ __forceinline__ unsigned int pack2bf(float a, float b) {
    unsigned int ua = __float_as_uint(a) + 0x8000u;
    unsigned int ub = __float_as_uint(b) + 0x8000u;
    return (ua >> 16) | (ub & 0xFFFF0000u);
}
// HW packed f32->bf16 (RNE), low16=cvt(a) high16=cvt(b)
__device__ __forceinline__ unsigned int cvtpk(float a, float b) {
    unsigned int r;
    asm("v_cvt_pk_bf16_f32 %0, %1, %2" : "=v"(r) : "v"(a), "v"(b));
    return r;
}

#if __has_builtin(__builtin_amdgcn_exp2f)
#define EXP2(x) __builtin_amdgcn_exp2f(x)
#else
#define EXP2(x) exp2f(x)
#endif

// async 16B global->LDS; vmcnt-tracked; LDS dest = wave-uniform base + lane*16
__device__ __forceinline__ void gl_lds16(const void* g, void* l) {
    __builtin_amdgcn_global_load_lds(
        (const __attribute__((address_space(1))) unsigned int*)g,
        (__attribute__((address_space(3))) unsigned int*)l, 16, 0, 0);
}

// ---------------- Kernel 0: weight prep -------------------------------------
// WT[h][192][512] bf16 (Q slice scaled by 0.125*log2e), then WOT[64][512].
__global__ __launch_bounds__(256) void wprep(
    const float* __restrict__ WQ, const float* __restrict__ WK,
    const float* __restrict__ WV, const float* __restrict__ WO,
    unsigned short* __restrict__ WT)
{
    __shared__ float tile[64][65];
    const int t  = threadIdx.x;
    const int d0 = blockIdx.x * 64;
    const int yy = blockIdx.y;

    const float* W; float scale = 1.0f; size_t dstbase;
    if (yy < 24) {
        int h = yy / 3, which = yy % 3;
        W = (which == 0) ? WQ : (which == 1) ? WK : WV;
        W += (size_t)h * Dn * 64;
        if (which == 0) scale = 0.125f * 1.44269504088896f;   // fold 1/8 * log2(e)
        dstbase = ((size_t)h * 192 + which * 64) * Dn;
    } else {
        W = WO;                                                // [512][64]
        dstbase = (size_t)8 * 192 * Dn;                        // WOT after QKV
    }

    for (int i = 0; i < 4; ++i) {
        int idx = i * 256 + t;
        int r = idx >> 4, c = (idx & 15) * 4;
        float4 u = *(const float4*)(W + (size_t)(d0 + r) * 64 + c);
        tile[r][c] = u.x; tile[r][c+1] = u.y; tile[r][c+2] = u.z; tile[r][c+3] = u.w;
    }
    __syncthreads();
    const int n = t & 63, dd = t >> 6;
    unsigned short pk[16];
    for (int i = 0; i < 16; ++i) pk[i] = f2bf(tile[dd*16 + i][n] * scale);
    size_t dst = dstbase + (size_t)n * Dn + d0 + dd * 16;
    *(bf16x8*)(WT + dst)     = *(bf16x8*)(pk);
    *(bf16x8*)(WT + dst + 8) = *(bf16x8*)(pk + 8);
}

// ---------------- Kernel 1: MFMA QKV projection (R27: XCD-swizzled grid) ----
// 1D grid 2048; id -> c=id&7, j=id>>3; bh=8c+(j&7), s0=(j>>3)*64. Co-resident
// blocks per XCD share x panels across heads (L2-resident 3.5MB set).
__global__ __launch_bounds__(256) void qkv_mfma(
    const float* __restrict__ x, const unsigned short* __restrict__ WT,
    unsigned short* __restrict__ Qb, unsigned short* __restrict__ Kb,
    unsigned short* __restrict__ VT)
{
    __shared__ __align__(16) unsigned short lds[64*72 + 192*72];
    unsigned short* Xs = lds;
    unsigned short* Ws = lds + 64*72;
    unsigned short* L  = lds;

    const int t  = threadIdx.x;
    const int w  = t >> 6, ln = t & 63;
    const int nl = ln & 15, g = ln >> 4;
    // XCD-bijective swizzle: XCD c = id&7 owns all 8 heads x all s-tiles of
    // batch c, ordered s-tile-major so co-resident blocks share x panels.
    const int id = blockIdx.x;
    const int c  = id & 7, j = id >> 3;
    const int bh = c * 8 + (j & 7), b = bh >> 3, h = bh & 7;
    const int s0 = (j >> 3) * 64;

    f32x4 acc[4][3];
    for (int m = 0; m < 4; ++m)
        for (int j2 = 0; j2 < 3; ++j2) acc[m][j2] = (f32x4){0.f, 0.f, 0.f, 0.f};

    for (int k0 = 0; k0 < Dn; k0 += 64) {
        __syncthreads();
        for (int i = 0; i < 2; ++i) {              // x tile fp32 -> bf16 (pack2)
            int idx = i * 256 + t;
            int r = idx >> 3, cc = (idx & 7) * 8;
            const float* src = x + ((size_t)(b * Sn + s0 + r)) * Dn + k0 + cc;
            float4 u0 = *(const float4*)(src);
            float4 u1 = *(const float4*)(src + 4);
            unsigned int pk[4] = { pack2bf(u0.x, u0.y), pack2bf(u0.z, u0.w),
                                   pack2bf(u1.x, u1.y), pack2bf(u1.z, u1.w) };
            *(bf16x8*)(Xs + r*72 + cc) = *(bf16x8*)pk;
        }
        for (int i = 0; i < 6; ++i) {              // WT tile 192x64
            int idx = i * 256 + t;
            int r = idx >> 3, cc = (idx & 7) * 8;
            *(bf16x8*)(Ws + r*72 + cc) =
                *(const bf16x8*)(WT + ((size_t)h * 192 + r) * Dn + k0 + cc);
        }
        __syncthreads();
        #pragma unroll
        for (int kc = 0; kc < 2; ++kc) {
            bf16x8 a[4], bb[3];
            for (int m = 0; m < 4; ++m)
                a[m]  = *(const bf16x8*)(Xs + (16*m + nl)*72 + 32*kc + 8*g);
            for (int j2 = 0; j2 < 3; ++j2)
                bb[j2] = *(const bf16x8*)(Ws + ((3*w + j2)*16 + nl)*72 + 32*kc + 8*g);
            for (int m = 0; m < 4; ++m)
                for (int j2 = 0; j2 < 3; ++j2)
                    acc[m][j2] = __builtin_amdgcn_mfma_f32_16x16x32_bf16(
                                    a[m], bb[j2], acc[m][j2], 0, 0, 0);
        }
    }
    __syncthreads();
    for (int m = 0; m < 4; ++m)                    // C: col=lane&15, row=4g+reg
        for (int j2 = 0; j2 < 3; ++j2) {
            int n = 48*w + 16*j2 + nl;
            for (int r = 0; r < 4; ++r)
                L[(16*m + 4*g + r)*200 + n] = f2bf(acc[m][j2][r]);
        }
    __syncthreads();
    for (int i = 0; i < 4; ++i) {                  // Qb/Kb row-major
        int idx = i * 256 + t;
        int r = idx >> 4, cc = (idx & 15) * 8;
        bf16x8 v = *(const bf16x8*)(L + r*200 + cc);
        size_t o = ((size_t)bh * Sn + s0 + r) * 64;
        if (cc < 64) *(bf16x8*)(Qb + o + cc)      = v;
        else         *(bf16x8*)(Kb + o + cc - 64) = v;
    }
    {   // VT[bh][o][s], sigma k-permuted within 32-blocks (for in-reg P in flash)
        int o = t & 63, cc = t >> 6;
        unsigned short pk[16];
        for (int i = 0; i < 16; ++i) {
            int srow = 32*(cc>>1) + 16*((i>>2)&1) + 8*(cc&1) + 4*((i>>3)&1) + (i&3);
            pk[i] = L[srow*200 + 128 + o];
        }
        size_t dst = ((size_t)bh * 64 + o) * Sn + s0 + 16*cc;
        *(bf16x8*)(VT + dst)     = *(bf16x8*)(pk);
        *(bf16x8*)(VT + dst + 8) = *(bf16x8*)(pk + 8);
    }
}

// ---------------- Kernel 2: MFMA flash attention (R26: XCD-swizzled grid) ---
// 8 waves x 32 q-rows (2 q-sets), 256 q/block, 1D grid 512, lid=(id&7)*64+id>>3
// -> XCD c owns bh[8c,8c+8) (L2-resident K/V working set). In-register P
// (sigma-permuted V). 3-buffer KV, depth-2 prefetch, one s_barrier/tile,
// vmcnt(2) counted. setprio on MFMA.
__global__ __launch_bounds__(512, 4) void flash_mfma(
    const unsigned short* __restrict__ Qb,
    const unsigned short* __restrict__ Kb,
    const unsigned short* __restrict__ VT,
    unsigned short* __restrict__ Ob)
{
    __shared__ __align__(16) unsigned short KV[3][2][4096];   // 48 KB

    const int t  = threadIdx.x;                    // 512 threads, 8 waves
    const int w  = t >> 6, ln = t & 63;
    const int qh = ln & 15, g = (ln >> 4) & 3;
    const int id  = blockIdx.x;
    const int lid = (id & 7) * 64 + (id >> 3);
    const int bh = lid >> 3, b = bh >> 3, h = bh & 7;
    const int q0 = (lid & 7) * 256;
    const int qw = q0 + 32 * w;                    // this wave's 32 q rows

    bf16x8 bq[2][2];
    #pragma unroll
    for (int qs = 0; qs < 2; ++qs) {
        const unsigned short* qp =
            Qb + ((size_t)bh * Sn + qw + 16*qs + qh) * 64 + 8*g;
        bq[qs][0] = *(const bf16x8*)(qp);
        bq[qs][1] = *(const bf16x8*)(qp + 32);
    }

    const int r0 = t >> 3;                         // tile row 0..63
    const int cs = (t & 7) ^ (r0 & 7);             // swizzled source chunk col
    const unsigned short* kg = Kb + ((size_t)bh * Sn + r0) * 64 + cs * 8;
    const unsigned short* vg = VT + ((size_t)bh * 64 + r0) * Sn + cs * 8;

    const int koff0 = qh*64 + (((g    ) ^ (qh & 7)) * 8);
    const int koff1 = qh*64 + (((4 + g) ^ (qh & 7)) * 8);

    f32x4 o_acc[2][4];
    #pragma unroll
    for (int qs = 0; qs < 2; ++qs)
        #pragma unroll
        for (int f = 0; f < 4; ++f) o_acc[qs][f] = (f32x4){0.f, 0.f, 0.f, 0.f};
    float l_run[2] = {0.f, 0.f};

    gl_lds16(kg,        &KV[0][0][w * 512]);
    gl_lds16(vg,        &KV[0][1][w * 512]);
    gl_lds16(kg + 4096, &KV[1][0][w * 512]);
    gl_lds16(vg + 64,   &KV[1][1][w * 512]);

    constexpr int NT = Sn / 64;                    // 32 tiles
    int buf = 0, sbuf = 2;
    for (int kt = 0; kt < NT; ++kt) {
        if (kt < NT - 1) asm volatile("s_waitcnt vmcnt(2)" ::: "memory");
        else             asm volatile("s_waitcnt vmcnt(0)" ::: "memory");
        __builtin_amdgcn_s_barrier();

        if (kt < NT - 2) {                         // stage tile kt+2 (async)
            gl_lds16(kg + (size_t)(kt + 2) * 4096, &KV[sbuf][0][w * 512]);
            gl_lds16(vg + (size_t)(kt + 2) * 64,   &KV[sbuf][1][w * 512]);
        }
        const unsigned short* Kt = KV[buf][0];
        const unsigned short* Vt = KV[buf][1];

        f32x4 st[2][4];
        #pragma unroll
        for (int qs = 0; qs < 2; ++qs)
            #pragma unroll
            for (int f = 0; f < 4; ++f) st[qs][f] = (f32x4){0.f, 0.f, 0.f, 0.f};
        __builtin_amdgcn_s_setprio(1);
        #pragma unroll
        for (int kc = 0; kc < 2; ++kc) {
            const int ko = kc ? koff1 : koff0;
            bf16x8 a0 = *(const bf16x8*)(Kt + ko);
            bf16x8 a1 = *(const bf16x8*)(Kt + ko + 1024);
            bf16x8 a2 = *(const bf16x8*)(Kt + ko + 2048);
            bf16x8 a3 = *(const bf16x8*)(Kt + ko + 3072);
            #pragma unroll
            for (int qs = 0; qs < 2; ++qs) {
                st[qs][0] = __builtin_amdgcn_mfma_f32_16x16x32_bf16(a0, bq[qs][kc], st[qs][0], 0, 0, 0);
                st[qs][1] = __builtin_amdgcn_mfma_f32_16x16x32_bf16(a1, bq[qs][kc], st[qs][1], 0, 0, 0);
                st[qs][2] = __builtin_amdgcn_mfma_f32_16x16x32_bf16(a2, bq[qs][kc], st[qs][2], 0, 0, 0);
                st[qs][3] = __builtin_amdgcn_mfma_f32_16x16x32_bf16(a3, bq[qs][kc], st[qs][3], 0, 0, 0);
            }
        }
        __builtin_amdgcn_s_setprio(0);

        bf16x8 bp[2][2];
        #pragma unroll
        for (int qs = 0; qs < 2; ++qs) {
            float e0[4], e1[4], e2[4], e3[4];
            #pragma unroll
            for (int r = 0; r < 4; ++r) {
                e0[r] = EXP2(st[qs][0][r]);
                e1[r] = EXP2(st[qs][1][r]);
                e2[r] = EXP2(st[qs][2][r]);
                e3[r] = EXP2(st[qs][3][r]);
            }
            l_run[qs] += ((e0[0]+e0[1])+(e0[2]+e0[3])) + ((e1[0]+e1[1])+(e1[2]+e1[3]))
                       + ((e2[0]+e2[1])+(e2[2]+e2[3])) + ((e3[0]+e3[1])+(e3[2]+e3[3]));
            unsigned int p0[4] = { cvtpk(e0[0],e0[1]), cvtpk(e0[2],e0[3]),
                                   cvtpk(e1[0],e1[1]), cvtpk(e1[2],e1[3]) };
            unsigned int p1[4] = { cvtpk(e2[0],e2[1]), cvtpk(e2[2],e2[3]),
                                   cvtpk(e3[0],e3[1]), cvtpk(e3[2],e3[3]) };
            bp[qs][0] = *(bf16x8*)p0;
            bp[qs][1] = *(bf16x8*)p1;
        }

        __builtin_amdgcn_s_setprio(1);
        #pragma unroll
        for (int kc = 0; kc < 2; ++kc) {
            const int ko = kc ? koff1 : koff0;
            bf16x8 v0 = *(const bf16x8*)(Vt + ko);
            bf16x8 v1 = *(const bf16x8*)(Vt + ko + 1024);
            bf16x8 v2 = *(const bf16x8*)(Vt + ko + 2048);
            bf16x8 v3 = *(const bf16x8*)(Vt + ko + 3072);
            #pragma unroll
            for (int qs = 0; qs < 2; ++qs) {
                o_acc[qs][0] = __builtin_amdgcn_mfma_f32_16x16x32_bf16(v0, bp[qs][kc], o_acc[qs][0], 0, 0, 0);
                o_acc[qs][1] = __builtin_amdgcn_mfma_f32_16x16x32_bf16(v1, bp[qs][kc], o_acc[qs][1], 0, 0, 0);
                o_acc[qs][2] = __builtin_amdgcn_mfma_f32_16x16x32_bf16(v2, bp[qs][kc], o_acc[qs][2], 0, 0, 0);
                o_acc[qs][3] = __builtin_amdgcn_mfma_f32_16x16x32_bf16(v3, bp[qs][kc], o_acc[qs][3], 0, 0, 0);
            }
        }
        __builtin_amdgcn_s_setprio(0);

        buf  = (buf  == 2) ? 0 : buf  + 1;
        sbuf = (sbuf == 2) ? 0 : sbuf + 1;
    }

    #pragma unroll
    for (int qs = 0; qs < 2; ++qs) {
        l_run[qs] += __shfl_xor(l_run[qs], 16);
        l_run[qs] += __shfl_xor(l_run[qs], 32);
    }

    #pragma unroll
    for (int qs = 0; qs < 2; ++qs) {
        float inv_l = 1.f / l_run[qs];
        unsigned short* op = Ob
            + ((size_t)(b * Sn + q0 + 32*w + 16*qs + qh)) * 512 + h*64 + 4*g;
        #pragma unroll
        for (int f = 0; f < 4; ++f) {
            unsigned int lo = cvtpk(o_acc[qs][f][0] * inv_l, o_acc[qs][f][1] * inv_l);
            unsigned int hi = cvtpk(o_acc[qs][f][2] * inv_l, o_acc[qs][f][3] * inv_l);
            *(uint2*)(op + 16*f) = make_uint2(lo, hi);
        }
    }
}

// ---------------- Kernel 3: MFMA output projection --------------------------
// out[bs][n] = Ob[bs][0:512] @ WOT^T ; A=Ob rows, B=WOT[n][k]. fp32 out.
__global__ __launch_bounds__(256) void out_mfma(
    const unsigned short* __restrict__ Ob, const unsigned short* __restrict__ WOT,
    float* __restrict__ out)
{
    __shared__ __align__(16) unsigned short As[64 * 72];
    __shared__ __align__(16) unsigned short Bs[64 * 72];

    const int t  = threadIdx.x;
    const int w  = t >> 6, ln = t & 63;
    const int qh = ln & 15, g = ln >> 4;
    const int bs0 = blockIdx.x * 64;

    f32x4 acc[4];
    for (int n = 0; n < 4; ++n) acc[n] = (f32x4){0.f, 0.f, 0.f, 0.f};

    for (int k0 = 0; k0 < 512; k0 += 64) {
        __syncthreads();
        for (int i = 0; i < 2; ++i) {
            int idx = i * 256 + t;
            int r = idx >> 3, c = (idx & 7) * 8;
            *(bf16x8*)(As + r*72 + c) =
                *(const bf16x8*)(Ob + ((size_t)(bs0 + r)) * 512 + k0 + c);
            *(bf16x8*)(Bs + r*72 + c) =
                *(const bf16x8*)(WOT + (size_t)r * Dn + k0 + c);
        }
        __syncthreads();
        #pragma unroll
        for (int kc = 0; kc < 2; ++kc) {
            bf16x8 a = *(const bf16x8*)(As + (16*w + qh)*72 + 32*kc + 8*g);
            #pragma unroll
            for (int n = 0; n < 4; ++n) {
                bf16x8 bb = *(const bf16x8*)(Bs + (16*n + qh)*72 + 32*kc + 8*g);
                acc[n] = __builtin_amdgcn_mfma_f32_16x16x32_bf16(a, bb, acc[n], 0, 0, 0);
            }
        }
    }
    // C: col=lane&15 -> n-col = 16nt+qh ; row = 4g+reg -> m = 16w+4g+r
    for (int n = 0; n < 4; ++n)
        for (int r = 0; r < 4; ++r)
            out[((size_t)(bs0 + 16*w + 4*g + r)) * 64 + 16*n + qh] = acc[n][r];
}

extern "C" void kernel_launch(void* const* d_in, const int* in_sizes, int n_in,
                              void* d_out, int out_size, void* d_ws, size_t ws_size,
                              hipStream_t stream)
{
    const float* x  = (const float*)d_in[0];
    const float* WQ = (const float*)d_in[1];
    const float* WK = (const float*)d_in[2];
    const float* WV = (const float*)d_in[3];
    const float* WO = (const float*)d_in[4];
    float* out = (float*)d_out;

    const size_t NQ = (size_t)Bn * Hn * Sn * LATn;     // 8,388,608
    char* p = (char*)d_ws;
    unsigned short* Qb  = (unsigned short*)p;           p += NQ * 2;            // 16MB
    unsigned short* Kb  = (unsigned short*)p;           p += NQ * 2;            // 16MB
    unsigned short* VT  = (unsigned short*)p;           p += NQ * 2;            // 16MB
    unsigned short* WT  = (unsigned short*)p;           p += ((size_t)Hn*192*Dn + 64*Dn) * 2;
    unsigned short* Ob  = (unsigned short*)p;                                   // 16MB
    unsigned short* WOT = WT + (size_t)Hn * 192 * Dn;

    wprep     <<<dim3(8, 25),    256, 0, stream>>>(WQ, WK, WV, WO, WT);
    qkv_mfma  <<<dim3(2048),     256, 0, stream>>>(x, WT, Qb, Kb, VT);
    flash_mfma<<<dim3(512),      512, 0, stream>>>(Qb, Kb, VT, Ob);
    out_mfma  <<<dim3(Bn*Sn/64), 256, 0, stream>>>(Ob, WOT, out);
}

// Round 15
// 196.600 us; speedup vs baseline: 1.0530x; 1.0530x over previous
//
#include <hip/hip_runtime.h>
#include <hip/hip_bf16.h>
#include <math.h>

// MHA B=8,S=2048,D=512,H=8,LAT=64,OUT=64. fp32 in/out.
// R28: byte-exact revert to R26 (session best: 201.6us).
// R27's qkv XCD swizzle was null-to-negative (x re-reads already L3-absorbed)
// -> reverted. Final composition:
//  - qkv: R14 structure + sigma-permuted VT epilogue
//  - flash: 8 waves x 32q, in-register P (sigma V), 3-buf KV, counted vmcnt(2),
//    setprio, XCD-bijective grid (FETCH 139->24.6MB, dur 77.5->73)
//  - out_mfma simple 2-barrier; wprep.
// Baseline 285.4 -> 201.6 (-29%). Flash at ~85% combined SIMD issue.
static constexpr int Bn = 8, Sn = 2048, Dn = 512, Hn = 8, LATn = 64, OUTn = 64;

typedef short  bf16x8 __attribute__((ext_vector_type(8)));
typedef float  f32x4  __attribute__((ext_vector_type(4)));

__device__ __forceinline__ unsigned short f2bf(float f) {   // RNE (prep kernels)
    union { float f; unsigned int i; } v; v.f = f;
    unsigned int x = v.i;
    return (unsigned short)((x + 0x7FFFu + ((x >> 16) & 1u)) >> 16);
}
// pack two floats -> two bf16 (round-half-up: bias 2^-17 rel, ~RNE quality)
__device__ __forceinline__ unsigned int pack2bf(float a, float b) {
    unsigned int ua = __float_as_uint(a) + 0x8000u;
    unsigned int ub = __float_as_uint(b) + 0x8000u;
    return (ua >> 16) | (ub & 0xFFFF0000u);
}
// HW packed f32->bf16 (RNE), low16=cvt(a) high16=cvt(b)
__device__ __forceinline__ unsigned int cvtpk(float a, float b) {
    unsigned int r;
    asm("v_cvt_pk_bf16_f32 %0, %1, %2" : "=v"(r) : "v"(a), "v"(b));
    return r;
}

#if __has_builtin(__builtin_amdgcn_exp2f)
#define EXP2(x) __builtin_amdgcn_exp2f(x)
#else
#define EXP2(x) exp2f(x)
#endif

// async 16B global->LDS; vmcnt-tracked; LDS dest = wave-uniform base + lane*16
__device__ __forceinline__ void gl_lds16(const void* g, void* l) {
    __builtin_amdgcn_global_load_lds(
        (const __attribute__((address_space(1))) unsigned int*)g,
        (__attribute__((address_space(3))) unsigned int*)l, 16, 0, 0);
}

// ---------------- Kernel 0: weight prep -------------------------------------
// WT[h][192][512] bf16 (Q slice scaled by 0.125*log2e), then WOT[64][512].
__global__ __launch_bounds__(256) void wprep(
    const float* __restrict__ WQ, const float* __restrict__ WK,
    const float* __restrict__ WV, const float* __restrict__ WO,
    unsigned short* __restrict__ WT)
{
    __shared__ float tile[64][65];
    const int t  = threadIdx.x;
    const int d0 = blockIdx.x * 64;
    const int yy = blockIdx.y;

    const float* W; float scale = 1.0f; size_t dstbase;
    if (yy < 24) {
        int h = yy / 3, which = yy % 3;
        W = (which == 0) ? WQ : (which == 1) ? WK : WV;
        W += (size_t)h * Dn * 64;
        if (which == 0) scale = 0.125f * 1.44269504088896f;   // fold 1/8 * log2(e)
        dstbase = ((size_t)h * 192 + which * 64) * Dn;
    } else {
        W = WO;                                                // [512][64]
        dstbase = (size_t)8 * 192 * Dn;                        // WOT after QKV
    }

    for (int i = 0; i < 4; ++i) {
        int idx = i * 256 + t;
        int r = idx >> 4, c = (idx & 15) * 4;
        float4 u = *(const float4*)(W + (size_t)(d0 + r) * 64 + c);
        tile[r][c] = u.x; tile[r][c+1] = u.y; tile[r][c+2] = u.z; tile[r][c+3] = u.w;
    }
    __syncthreads();
    const int n = t & 63, dd = t >> 6;
    unsigned short pk[16];
    for (int i = 0; i < 16; ++i) pk[i] = f2bf(tile[dd*16 + i][n] * scale);
    size_t dst = dstbase + (size_t)n * Dn + d0 + dd * 16;
    *(bf16x8*)(WT + dst)     = *(bf16x8*)(pk);
    *(bf16x8*)(WT + dst + 8) = *(bf16x8*)(pk + 8);
}

// ---------------- Kernel 1: MFMA QKV projection (R14 + sigma on VT) ---------
__global__ __launch_bounds__(256) void qkv_mfma(
    const float* __restrict__ x, const unsigned short* __restrict__ WT,
    unsigned short* __restrict__ Qb, unsigned short* __restrict__ Kb,
    unsigned short* __restrict__ VT)
{
    __shared__ __align__(16) unsigned short lds[64*72 + 192*72];
    unsigned short* Xs = lds;
    unsigned short* Ws = lds + 64*72;
    unsigned short* L  = lds;

    const int t  = threadIdx.x;
    const int w  = t >> 6, ln = t & 63;
    const int nl = ln & 15, g = ln >> 4;
    const int bh = blockIdx.y, b = bh >> 3, h = bh & 7;
    const int s0 = blockIdx.x * 64;

    f32x4 acc[4][3];
    for (int m = 0; m < 4; ++m)
        for (int j = 0; j < 3; ++j) acc[m][j] = (f32x4){0.f, 0.f, 0.f, 0.f};

    for (int k0 = 0; k0 < Dn; k0 += 64) {
        __syncthreads();
        for (int i = 0; i < 2; ++i) {              // x tile fp32 -> bf16 (pack2)
            int idx = i * 256 + t;
            int r = idx >> 3, c = (idx & 7) * 8;
            const float* src = x + ((size_t)(b * Sn + s0 + r)) * Dn + k0 + c;
            float4 u0 = *(const float4*)(src);
            float4 u1 = *(const float4*)(src + 4);
            unsigned int pk[4] = { pack2bf(u0.x, u0.y), pack2bf(u0.z, u0.w),
                                   pack2bf(u1.x, u1.y), pack2bf(u1.z, u1.w) };
            *(bf16x8*)(Xs + r*72 + c) = *(bf16x8*)pk;
        }
        for (int i = 0; i < 6; ++i) {              // WT tile 192x64
            int idx = i * 256 + t;
            int r = idx >> 3, c = (idx & 7) * 8;
            *(bf16x8*)(Ws + r*72 + c) =
                *(const bf16x8*)(WT + ((size_t)h * 192 + r) * Dn + k0 + c);
        }
        __syncthreads();
        #pragma unroll
        for (int kc = 0; kc < 2; ++kc) {
            bf16x8 a[4], bb[3];
            for (int m = 0; m < 4; ++m)
                a[m]  = *(const bf16x8*)(Xs + (16*m + nl)*72 + 32*kc + 8*g);
            for (int j = 0; j < 3; ++j)
                bb[j] = *(const bf16x8*)(Ws + ((3*w + j)*16 + nl)*72 + 32*kc + 8*g);
            for (int m = 0; m < 4; ++m)
                for (int j = 0; j < 3; ++j)
                    acc[m][j] = __builtin_amdgcn_mfma_f32_16x16x32_bf16(
                                    a[m], bb[j], acc[m][j], 0, 0, 0);
        }
    }
    __syncthreads();
    for (int m = 0; m < 4; ++m)                    // C: col=lane&15, row=4g+reg
        for (int j = 0; j < 3; ++j) {
            int n = 48*w + 16*j + nl;
            for (int r = 0; r < 4; ++r)
                L[(16*m + 4*g + r)*200 + n] = f2bf(acc[m][j][r]);
        }
    __syncthreads();
    for (int i = 0; i < 4; ++i) {                  // Qb/Kb row-major
        int idx = i * 256 + t;
        int r = idx >> 4, c = (idx & 15) * 8;
        bf16x8 v = *(const bf16x8*)(L + r*200 + c);
        size_t o = ((size_t)bh * Sn + s0 + r) * 64;
        if (c < 64) *(bf16x8*)(Qb + o + c)      = v;
        else        *(bf16x8*)(Kb + o + c - 64) = v;
    }
    {   // VT[bh][o][s], sigma k-permuted within 32-blocks (for in-reg P in flash)
        int o = t & 63, cc = t >> 6;
        unsigned short pk[16];
        for (int i = 0; i < 16; ++i) {
            int srow = 32*(cc>>1) + 16*((i>>2)&1) + 8*(cc&1) + 4*((i>>3)&1) + (i&3);
            pk[i] = L[srow*200 + 128 + o];
        }
        size_t dst = ((size_t)bh * 64 + o) * Sn + s0 + 16*cc;
        *(bf16x8*)(VT + dst)     = *(bf16x8*)(pk);
        *(bf16x8*)(VT + dst + 8) = *(bf16x8*)(pk + 8);
    }
}

// ---------------- Kernel 2: MFMA flash attention (R26: XCD-swizzled grid) ---
// 8 waves x 32 q-rows (2 q-sets), 256 q/block, 1D grid 512, lid=(id&7)*64+id>>3
// -> XCD c owns bh[8c,8c+8) (L2-resident K/V working set). In-register P
// (sigma-permuted V). 3-buffer KV, depth-2 prefetch, one s_barrier/tile,
// vmcnt(2) counted. setprio on MFMA.
__global__ __launch_bounds__(512, 4) void flash_mfma(
    const unsigned short* __restrict__ Qb,
    const unsigned short* __restrict__ Kb,
    const unsigned short* __restrict__ VT,
    unsigned short* __restrict__ Ob)
{
    __shared__ __align__(16) unsigned short KV[3][2][4096];   // 48 KB

    const int t  = threadIdx.x;                    // 512 threads, 8 waves
    const int w  = t >> 6, ln = t & 63;
    const int qh = ln & 15, g = (ln >> 4) & 3;
    // XCD-bijective swizzle (512 blocks, 8 XCDs): hw id -> XCD id&7; logical
    // lid gives XCD c the contiguous range [c*64,(c+1)*64) = bh [8c,8c+8).
    const int id  = blockIdx.x;
    const int lid = (id & 7) * 64 + (id >> 3);
    const int bh = lid >> 3, b = bh >> 3, h = bh & 7;
    const int q0 = (lid & 7) * 256;
    const int qw = q0 + 32 * w;                    // this wave's 32 q rows

    bf16x8 bq[2][2];
    #pragma unroll
    for (int qs = 0; qs < 2; ++qs) {
        const unsigned short* qp =
            Qb + ((size_t)bh * Sn + qw + 16*qs + qh) * 64 + 8*g;
        bq[qs][0] = *(const bf16x8*)(qp);
        bq[qs][1] = *(const bf16x8*)(qp + 32);
    }

    const int r0 = t >> 3;                         // tile row 0..63
    const int cs = (t & 7) ^ (r0 & 7);             // swizzled source chunk col
    const unsigned short* kg = Kb + ((size_t)bh * Sn + r0) * 64 + cs * 8;
    const unsigned short* vg = VT + ((size_t)bh * 64 + r0) * Sn + cs * 8;

    const int koff0 = qh*64 + (((g    ) ^ (qh & 7)) * 8);
    const int koff1 = qh*64 + (((4 + g) ^ (qh & 7)) * 8);

    f32x4 o_acc[2][4];
    #pragma unroll
    for (int qs = 0; qs < 2; ++qs)
        #pragma unroll
        for (int f = 0; f < 4; ++f) o_acc[qs][f] = (f32x4){0.f, 0.f, 0.f, 0.f};
    float l_run[2] = {0.f, 0.f};

    gl_lds16(kg,        &KV[0][0][w * 512]);
    gl_lds16(vg,        &KV[0][1][w * 512]);
    gl_lds16(kg + 4096, &KV[1][0][w * 512]);
    gl_lds16(vg + 64,   &KV[1][1][w * 512]);

    constexpr int NT = Sn / 64;                    // 32 tiles
    int buf = 0, sbuf = 2;
    for (int kt = 0; kt < NT; ++kt) {
        if (kt < NT - 1) asm volatile("s_waitcnt vmcnt(2)" ::: "memory");
        else             asm volatile("s_waitcnt vmcnt(0)" ::: "memory");
        __builtin_amdgcn_s_barrier();

        if (kt < NT - 2) {                         // stage tile kt+2 (async)
            gl_lds16(kg + (size_t)(kt + 2) * 4096, &KV[sbuf][0][w * 512]);
            gl_lds16(vg + (size_t)(kt + 2) * 64,   &KV[sbuf][1][w * 512]);
        }
        const unsigned short* Kt = KV[buf][0];
        const unsigned short* Vt = KV[buf][1];

        f32x4 st[2][4];
        #pragma unroll
        for (int qs = 0; qs < 2; ++qs)
            #pragma unroll
            for (int f = 0; f < 4; ++f) st[qs][f] = (f32x4){0.f, 0.f, 0.f, 0.f};
        __builtin_amdgcn_s_setprio(1);
        #pragma unroll
        for (int kc = 0; kc < 2; ++kc) {
            const int ko = kc ? koff1 : koff0;
            bf16x8 a0 = *(const bf16x8*)(Kt + ko);
            bf16x8 a1 = *(const bf16x8*)(Kt + ko + 1024);
            bf16x8 a2 = *(const bf16x8*)(Kt + ko + 2048);
            bf16x8 a3 = *(const bf16x8*)(Kt + ko + 3072);
            #pragma unroll
            for (int qs = 0; qs < 2; ++qs) {
                st[qs][0] = __builtin_amdgcn_mfma_f32_16x16x32_bf16(a0, bq[qs][kc], st[qs][0], 0, 0, 0);
                st[qs][1] = __builtin_amdgcn_mfma_f32_16x16x32_bf16(a1, bq[qs][kc], st[qs][1], 0, 0, 0);
                st[qs][2] = __builtin_amdgcn_mfma_f32_16x16x32_bf16(a2, bq[qs][kc], st[qs][2], 0, 0, 0);
                st[qs][3] = __builtin_amdgcn_mfma_f32_16x16x32_bf16(a3, bq[qs][kc], st[qs][3], 0, 0, 0);
            }
        }
        __builtin_amdgcn_s_setprio(0);

        bf16x8 bp[2][2];
        #pragma unroll
        for (int qs = 0; qs < 2; ++qs) {
            float e0[4], e1[4], e2[4], e3[4];
            #pragma unroll
            for (int r = 0; r < 4; ++r) {
                e0[r] = EXP2(st[qs][0][r]);
                e1[r] = EXP2(st[qs][1][r]);
                e2[r] = EXP2(st[qs][2][r]);
                e3[r] = EXP2(st[qs][3][r]);
            }
            l_run[qs] += ((e0[0]+e0[1])+(e0[2]+e0[3])) + ((e1[0]+e1[1])+(e1[2]+e1[3]))
                       + ((e2[0]+e2[1])+(e2[2]+e2[3])) + ((e3[0]+e3[1])+(e3[2]+e3[3]));
            unsigned int p0[4] = { cvtpk(e0[0],e0[1]), cvtpk(e0[2],e0[3]),
                                   cvtpk(e1[0],e1[1]), cvtpk(e1[2],e1[3]) };
            unsigned int p1[4] = { cvtpk(e2[0],e2[1]), cvtpk(e2[2],e2[3]),
                                   cvtpk(e3[0],e3[1]), cvtpk(e3[2],e3[3]) };
            bp[qs][0] = *(bf16x8*)p0;
            bp[qs][1] = *(bf16x8*)p1;
        }

        __builtin_amdgcn_s_setprio(1);
        #pragma unroll
        for (int kc = 0; kc < 2; ++kc) {
            const int ko = kc ? koff1 : koff0;
            bf16x8 v0 = *(const bf16x8*)(Vt + ko);
            bf16x8 v1 = *(const bf16x8*)(Vt + ko + 1024);
            bf16x8 v2 = *(const bf16x8*)(Vt + ko + 2048);
            bf16x8 v3 = *(const bf16x8*)(Vt + ko + 3072);
            #pragma unroll
            for (int qs = 0; qs < 2; ++qs) {
                o_acc[qs][0] = __builtin_amdgcn_mfma_f32_16x16x32_bf16(v0, bp[qs][kc], o_acc[qs][0], 0, 0, 0);
                o_acc[qs][1] = __builtin_amdgcn_mfma_f32_16x16x32_bf16(v1, bp[qs][kc], o_acc[qs][1], 0, 0, 0);
                o_acc[qs][2] = __builtin_amdgcn_mfma_f32_16x16x32_bf16(v2, bp[qs][kc], o_acc[qs][2], 0, 0, 0);
                o_acc[qs][3] = __builtin_amdgcn_mfma_f32_16x16x32_bf16(v3, bp[qs][kc], o_acc[qs][3], 0, 0, 0);
            }
        }
        __builtin_amdgcn_s_setprio(0);

        buf  = (buf  == 2) ? 0 : buf  + 1;
        sbuf = (sbuf == 2) ? 0 : sbuf + 1;
    }

    #pragma unroll
    for (int qs = 0; qs < 2; ++qs) {
        l_run[qs] += __shfl_xor(l_run[qs], 16);
        l_run[qs] += __shfl_xor(l_run[qs], 32);
    }

    #pragma unroll
    for (int qs = 0; qs < 2; ++qs) {
        float inv_l = 1.f / l_run[qs];
        unsigned short* op = Ob
            + ((size_t)(b * Sn + q0 + 32*w + 16*qs + qh)) * 512 + h*64 + 4*g;
        #pragma unroll
        for (int f = 0; f < 4; ++f) {
            unsigned int lo = cvtpk(o_acc[qs][f][0] * inv_l, o_acc[qs][f][1] * inv_l);
            unsigned int hi = cvtpk(o_acc[qs][f][2] * inv_l, o_acc[qs][f][3] * inv_l);
            *(uint2*)(op + 16*f) = make_uint2(lo, hi);
        }
    }
}

// ---------------- Kernel 3: MFMA output projection --------------------------
// out[bs][n] = Ob[bs][0:512] @ WOT^T ; A=Ob rows, B=WOT[n][k]. fp32 out.
__global__ __launch_bounds__(256) void out_mfma(
    const unsigned short* __restrict__ Ob, const unsigned short* __restrict__ WOT,
    float* __restrict__ out)
{
    __shared__ __align__(16) unsigned short As[64 * 72];
    __shared__ __align__(16) unsigned short Bs[64 * 72];

    const int t  = threadIdx.x;
    const int w  = t >> 6, ln = t & 63;
    const int qh = ln & 15, g = ln >> 4;
    const int bs0 = blockIdx.x * 64;

    f32x4 acc[4];
    for (int n = 0; n < 4; ++n) acc[n] = (f32x4){0.f, 0.f, 0.f, 0.f};

    for (int k0 = 0; k0 < 512; k0 += 64) {
        __syncthreads();
        for (int i = 0; i < 2; ++i) {
            int idx = i * 256 + t;
            int r = idx >> 3, c = (idx & 7) * 8;
            *(bf16x8*)(As + r*72 + c) =
                *(const bf16x8*)(Ob + ((size_t)(bs0 + r)) * 512 + k0 + c);
            *(bf16x8*)(Bs + r*72 + c) =
                *(const bf16x8*)(WOT + (size_t)r * Dn + k0 + c);
        }
        __syncthreads();
        #pragma unroll
        for (int kc = 0; kc < 2; ++kc) {
            bf16x8 a = *(const bf16x8*)(As + (16*w + qh)*72 + 32*kc + 8*g);
            #pragma unroll
            for (int n = 0; n < 4; ++n) {
                bf16x8 bb = *(const bf16x8*)(Bs + (16*n + qh)*72 + 32*kc + 8*g);
                acc[n] = __builtin_amdgcn_mfma_f32_16x16x32_bf16(a, bb, acc[n], 0, 0, 0);
            }
        }
    }
    // C: col=lane&15 -> n-col = 16nt+qh ; row = 4g+reg -> m = 16w+4g+r
    for (int n = 0; n < 4; ++n)
        for (int r = 0; r < 4; ++r)
            out[((size_t)(bs0 + 16*w + 4*g + r)) * 64 + 16*n + qh] = acc[n][r];
}

extern "C" void kernel_launch(void* const* d_in, const int* in_sizes, int n_in,
                              void* d_out, int out_size, void* d_ws, size_t ws_size,
                              hipStream_t stream)
{
    const float* x  = (const float*)d_in[0];
    const float* WQ = (const float*)d_in[1];
    const float* WK = (const float*)d_in[2];
    const float* WV = (const float*)d_in[3];
    const float* WO = (const float*)d_in[4];
    float* out = (float*)d_out;

    const size_t NQ = (size_t)Bn * Hn * Sn * LATn;     // 8,388,608
    char* p = (char*)d_ws;
    unsigned short* Qb  = (unsigned short*)p;           p += NQ * 2;            // 16MB
    unsigned short* Kb  = (unsigned short*)p;           p += NQ * 2;            // 16MB
    unsigned short* VT  = (unsigned short*)p;           p += NQ * 2;            // 16MB
    unsigned short* WT  = (unsigned short*)p;           p += ((size_t)Hn*192*Dn + 64*Dn) * 2;
    unsigned short* Ob  = (unsigned short*)p;                                   // 16MB
    unsigned short* WOT = WT + (size_t)Hn * 192 * Dn;

    wprep     <<<dim3(8, 25),    256, 0, stream>>>(WQ, WK, WV, WO, WT);
    qkv_mfma  <<<dim3(Sn/64, Bn*Hn), 256, 0, stream>>>(x, WT, Qb, Kb, VT);
    flash_mfma<<<dim3(512),      512, 0, stream>>>(Qb, Kb, VT, Ob);
    out_mfma  <<<dim3(Bn*Sn/64), 256, 0, stream>>>(Ob, WOT, out);
}